// Round 1
// baseline (624.127 us; speedup 1.0000x reference)
//
#include <hip/hip_runtime.h>
#include <cstdint>

typedef unsigned short u16;
typedef unsigned int u32;
typedef __attribute__((ext_vector_type(4))) float f32x4;
typedef __attribute__((ext_vector_type(8))) __bf16 bf16x8;
typedef __attribute__((ext_vector_type(8))) u16 u16x8;

#define DEV __device__ __forceinline__

DEV u16 f2bf(float f) {
  u32 u = __builtin_bit_cast(u32, f);
  u += 0x7fffu + ((u >> 16) & 1u);
  return (u16)(u >> 16);
}
DEV float bflo2f(u32 packed) { return __builtin_bit_cast(float, packed << 16); }
DEV float bfhi2f(u32 packed) { return __builtin_bit_cast(float, packed & 0xffff0000u); }

// async global->LDS, 16B per lane. lds pointer must be the WAVE-UNIFORM base;
// HW adds lane*16. Global pointer is per-lane.
DEV void g2l16(void* lds_wave_base, const void* gsrc) {
  __builtin_amdgcn_global_load_lds(
      (const __attribute__((address_space(1))) u32*)gsrc,
      (__attribute__((address_space(3))) u32*)lds_wave_base, 16, 0, 0);
}

// ---------------- depthwise conv 3x3 (first 192 ch) + passthrough ----------
__global__ __launch_bounds__(256) void conv_k(const float* __restrict__ x,
                                              const float* __restrict__ cw,
                                              const float* __restrict__ cb,
                                              float* __restrict__ xc) {
  int id = blockIdx.x * 256 + threadIdx.x;       // 32*384*1024 total
  int p = id & 1023;
  int bc = id >> 10;
  int c = bc % 384;
  float v;
  if (c < 192) {
    int hh = p >> 5, ww = p & 31;
    float a = cb[c];
    const float* xp = x + ((size_t)bc << 10);
    const float* wp = cw + c * 9;
#pragma unroll
    for (int dy = 0; dy < 3; ++dy) {
      int y = hh + dy - 1;
      if ((unsigned)y < 32u) {
#pragma unroll
        for (int dx = 0; dx < 3; ++dx) {
          int xw = ww + dx - 1;
          if ((unsigned)xw < 32u) a += xp[y * 32 + xw] * wp[dy * 3 + dx];
        }
      }
    }
    v = a;
  } else {
    v = x[id];
  }
  xc[id] = v;
}

// ---------------- f32 -> bf16 convert ----------------
__global__ __launch_bounds__(256) void cvt_k(const float* __restrict__ in,
                                             u16* __restrict__ out, int n) {
  int id = blockIdx.x * 256 + threadIdx.x;
  if (id < n) out[id] = f2bf(in[id]);
}

// ---------------- channel-LN (NCHW) + transpose to [token][C] bf16 ---------
// block: 256 thr, handles one b and 32 pixels; LDS tile [384][33] f32.
__global__ __launch_bounds__(256) void ln_t_k(const float* __restrict__ X,
                                              const float* __restrict__ w,
                                              const float* __restrict__ bsh,
                                              u16* __restrict__ Y) {
  __shared__ float tile[384][33];
  __shared__ float ps[8][32], ps2[8][32];
  __shared__ float mean_s[32], rstd_s[32];
  const int b = blockIdx.y;
  const int p0 = blockIdx.x * 32;
  const int t = threadIdx.x;
  const int pl = t & 31, cg = t >> 5;
  const float* xb = X + (((size_t)b * 384) << 10) + p0 + pl;
  float s = 0.f, s2 = 0.f;
  for (int c = cg; c < 384; c += 8) {
    float v = xb[(size_t)c << 10];
    tile[c][pl] = v;
    s += v;
    s2 += v * v;
  }
  ps[cg][pl] = s;
  ps2[cg][pl] = s2;
  __syncthreads();
  if (t < 32) {
    float a = 0.f, a2 = 0.f;
#pragma unroll
    for (int g = 0; g < 8; ++g) { a += ps[g][t]; a2 += ps2[g][t]; }
    float mu = a * (1.f / 384.f);
    float var = a2 * (1.f / 384.f) - mu * mu;
    mean_s[t] = mu;
    rstd_s[t] = rsqrtf(var + 1e-6f);
  }
  __syncthreads();
  const int cl = t & 63, pg = t >> 6;
  for (int p = pg; p < 32; p += 4) {
    float mu = mean_s[p], rs = rstd_s[p];
    size_t orow = (((size_t)b << 10) + p0 + p) * 384;
#pragma unroll
    for (int cc = 0; cc < 6; ++cc) {
      int c = cc * 64 + cl;
      float v = (tile[c][p] - mu) * rs * w[c] + bsh[c];
      Y[orow + c] = f2bf(v);
    }
  }
}

// ---------------- row-wise L2 normalize q,k in QKV (in place) --------------
// one wave per token; lane l owns elems [6l, 6l+6) => lanes 0..15 = head 0...
__global__ __launch_bounds__(256) void normqk_k(u16* __restrict__ QKV) {
  const int t = threadIdx.x;
  const int w = t >> 6, l = t & 63;
  const size_t token = (size_t)blockIdx.x * 4 + w;
  u16* bp = QKV + token * 1152;
#pragma unroll
  for (int seg = 0; seg < 2; ++seg) {
    u16* p = bp + seg * 384 + l * 6;
    u32 a = *(const u32*)p;
    u32 b2 = *(const u32*)(p + 2);
    u32 c = *(const u32*)(p + 4);
    float v[6] = {bflo2f(a), bfhi2f(a), bflo2f(b2), bfhi2f(b2), bflo2f(c), bfhi2f(c)};
    float ss = 0.f;
#pragma unroll
    for (int i = 0; i < 6; ++i) ss += v[i] * v[i];
#pragma unroll
    for (int mk = 1; mk < 16; mk <<= 1) ss += __shfl_xor(ss, mk, 64);
    float sc = 1.0f / fmaxf(sqrtf(ss), 1e-12f);
    u32 o0 = (u32)f2bf(v[0] * sc) | ((u32)f2bf(v[1] * sc) << 16);
    u32 o1 = (u32)f2bf(v[2] * sc) | ((u32)f2bf(v[3] * sc) << 16);
    u32 o2 = (u32)f2bf(v[4] * sc) | ((u32)f2bf(v[5] * sc) << 16);
    *(u32*)p = o0;
    *(u32*)(p + 2) = o1;
    *(u32*)(p + 4) = o2;
  }
}

// ---------------- flash attention per (qtile, head, batch) -----------------
// 4 waves; wave owns 16 q-rows. K tile [64][104] (padded), V^T tile [96][88],
// per-wave P [16][88]. Online softmax in f32 registers.
__global__ __launch_bounds__(256) void attn_k(const u16* __restrict__ QKV,
                                              u16* __restrict__ O,
                                              const float* __restrict__ temp) {
  __shared__ u16 Kt[64 * 104];
  __shared__ u16 Vt[96 * 88];
  __shared__ u16 Pt[4][16 * 88];
  const int t = threadIdx.x;
  const int w = t >> 6, l = t & 63;
  const int l15 = l & 15, kg = l >> 4;
  const int qt = blockIdx.x, h = blockIdx.y, b = blockIdx.z;
  const int q0 = qt * 64;
  const size_t base = (size_t)b * 1024 * 1152;

  bf16x8 qf[3];
  {
    int tok = q0 + w * 16 + l15;
    const u16* qp = QKV + base + (size_t)tok * 1152 + h * 96 + kg * 8;
#pragma unroll
    for (int kk = 0; kk < 3; ++kk) qf[kk] = *(const bf16x8*)(qp + kk * 32);
  }
  float m_r[4], l_r[4];
#pragma unroll
  for (int j = 0; j < 4; ++j) { m_r[j] = -3.0e38f; l_r[j] = 0.f; }
  f32x4 oa[6];
#pragma unroll
  for (int d = 0; d < 6; ++d) oa[d] = {0.f, 0.f, 0.f, 0.f};
  const float tmp = temp[h];

  const int row4 = t >> 2, q4 = t & 3;
  for (int kv0 = 0; kv0 < 1024; kv0 += 64) {
    {  // stage K tile (row-major) and V tile (transposed)
      const u16* sk = QKV + base + (size_t)(kv0 + row4) * 1152 + 384 + h * 96 + q4 * 24;
      u16* dk = Kt + row4 * 104 + q4 * 24;
#pragma unroll
      for (int i = 0; i < 3; ++i) *(u16x8*)(dk + i * 8) = *(const u16x8*)(sk + i * 8);
      const u16* sv = QKV + base + (size_t)(kv0 + row4) * 1152 + 768 + h * 96 + q4 * 24;
#pragma unroll
      for (int i = 0; i < 3; ++i) {
        u16x8 v = *(const u16x8*)(sv + i * 8);
#pragma unroll
        for (int jj = 0; jj < 8; ++jj) Vt[(q4 * 24 + i * 8 + jj) * 88 + row4] = v[jj];
      }
    }
    __syncthreads();
    // S = Qn @ Kn^T
    f32x4 s[4];
#pragma unroll
    for (int n = 0; n < 4; ++n) s[n] = {0.f, 0.f, 0.f, 0.f};
#pragma unroll
    for (int kk = 0; kk < 3; ++kk) {
#pragma unroll
      for (int n = 0; n < 4; ++n) {
        bf16x8 kf = *(const bf16x8*)(Kt + (n * 16 + l15) * 104 + kk * 32 + kg * 8);
        s[n] = __builtin_amdgcn_mfma_f32_16x16x32_bf16(qf[kk], kf, s[n], 0, 0, 0);
      }
    }
#pragma unroll
    for (int n = 0; n < 4; ++n)
#pragma unroll
      for (int j = 0; j < 4; ++j) s[n][j] *= tmp;
    // online softmax (rows live in 16-lane groups)
#pragma unroll
    for (int j = 0; j < 4; ++j) {
      float mx = fmaxf(fmaxf(s[0][j], s[1][j]), fmaxf(s[2][j], s[3][j]));
#pragma unroll
      for (int mk = 1; mk < 16; mk <<= 1) mx = fmaxf(mx, __shfl_xor(mx, mk, 64));
      float nm = fmaxf(m_r[j], mx);
      float corr = expf(m_r[j] - nm);
      m_r[j] = nm;
      float sum = 0.f;
#pragma unroll
      for (int n = 0; n < 4; ++n) {
        float pv = expf(s[n][j] - nm);
        s[n][j] = pv;
        sum += pv;
      }
#pragma unroll
      for (int mk = 1; mk < 16; mk <<= 1) sum += __shfl_xor(sum, mk, 64);
      l_r[j] = l_r[j] * corr + sum;
#pragma unroll
      for (int d = 0; d < 6; ++d) oa[d][j] *= corr;
    }
    // P -> LDS (per-wave region)
#pragma unroll
    for (int n = 0; n < 4; ++n)
#pragma unroll
      for (int j = 0; j < 4; ++j)
        Pt[w][(kg * 4 + j) * 88 + n * 16 + l15] = f2bf(s[n][j]);
    // O += P @ V
#pragma unroll
    for (int kk = 0; kk < 2; ++kk) {
      bf16x8 pf = *(const bf16x8*)(&Pt[w][l15 * 88 + kk * 32 + kg * 8]);
#pragma unroll
      for (int d = 0; d < 6; ++d) {
        bf16x8 vf = *(const bf16x8*)(Vt + (d * 16 + l15) * 88 + kk * 32 + kg * 8);
        oa[d] = __builtin_amdgcn_mfma_f32_16x16x32_bf16(pf, vf, oa[d], 0, 0, 0);
      }
    }
    __syncthreads();
  }
#pragma unroll
  for (int d = 0; d < 6; ++d) {
#pragma unroll
    for (int j = 0; j < 4; ++j) {
      int tok = q0 + w * 16 + kg * 4 + j;
      float v = oa[d][j] / l_r[j];
      O[((size_t)b * 1024 + tok) * 384 + h * 96 + d * 16 + l15] = f2bf(v);
    }
  }
}

// ---------------- 128x128x32 bf16 GEMM, m97 2-barrier structure ------------
// A [Mdim][K] row-major bf16, B [Ndim][K] row-major bf16, D = A @ B^T.
// EPI 0: D+bias -> bf16 row-major [M][N]
// EPI 1: gelu(D+bias) -> bf16 row-major [M][N]
// EPI 2: rows are channels, cols are tokens; out/res are NCHW f32:
//        out[b,c,p] = res[b,c,p] + gamma[c]*(D+bias[c])
template <int EPI>
__global__ __launch_bounds__(256) void gemm_k(const u16* __restrict__ A,
                                              const u16* __restrict__ B, int M,
                                              int N, int K,
                                              const float* __restrict__ bias,
                                              const float* gamma,
                                              const float* res, void* outp) {
  __shared__ u16 At[128 * 32];
  __shared__ u16 Bt[128 * 32];
  const int t = threadIdx.x;
  const int w = t >> 6, l = t & 63;
  const int l15 = l & 15, kg = l >> 4;
  const int m0 = blockIdx.y * 128, n0 = blockIdx.x * 128;
  const int wr = w >> 1, wc = w & 1;

  const int off1 = w * 1024 + l * 16;
  const int off2 = 4096 + w * 1024 + l * 16;
  const int r1 = off1 >> 6, c1 = off1 & 63;
  const int r2 = off2 >> 6, c2 = off2 & 63;
  const size_t ldab = (size_t)K * 2;
  const char* pa1 = (const char*)A + (size_t)(m0 + r1) * ldab + c1;
  const char* pa2 = (const char*)A + (size_t)(m0 + r2) * ldab + c2;
  const char* pb1 = (const char*)B + (size_t)(n0 + r1) * ldab + c1;
  const char* pb2 = (const char*)B + (size_t)(n0 + r2) * ldab + c2;
  char* At1 = (char*)At + w * 1024;
  char* At2 = (char*)At + 4096 + w * 1024;
  char* Bt1 = (char*)Bt + w * 1024;
  char* Bt2 = (char*)Bt + 4096 + w * 1024;

  f32x4 acc[4][4];
#pragma unroll
  for (int m = 0; m < 4; ++m)
#pragma unroll
    for (int n = 0; n < 4; ++n) acc[m][n] = {0.f, 0.f, 0.f, 0.f};

  const int nkt = K >> 5;
  for (int kt = 0; kt < nkt; ++kt) {
    g2l16(At1, pa1);
    g2l16(At2, pa2);
    g2l16(Bt1, pb1);
    g2l16(Bt2, pb2);
    pa1 += 64; pa2 += 64; pb1 += 64; pb2 += 64;
    __syncthreads();
    bf16x8 af[4], bfr[4];
#pragma unroll
    for (int m = 0; m < 4; ++m)
      af[m] = *(const bf16x8*)(At + (wr * 64 + m * 16 + l15) * 32 + kg * 8);
#pragma unroll
    for (int n = 0; n < 4; ++n)
      bfr[n] = *(const bf16x8*)(Bt + (wc * 64 + n * 16 + l15) * 32 + kg * 8);
#pragma unroll
    for (int m = 0; m < 4; ++m)
#pragma unroll
      for (int n = 0; n < 4; ++n)
        acc[m][n] = __builtin_amdgcn_mfma_f32_16x16x32_bf16(af[m], bfr[n], acc[m][n], 0, 0, 0);
    __syncthreads();
  }

  if (EPI <= 1) {
    u16* out = (u16*)outp;
#pragma unroll
    for (int m = 0; m < 4; ++m) {
#pragma unroll
      for (int n = 0; n < 4; ++n) {
        int gcol = n0 + wc * 64 + n * 16 + l15;
        float bs = bias[gcol];
#pragma unroll
        for (int j = 0; j < 4; ++j) {
          int grow = m0 + wr * 64 + m * 16 + kg * 4 + j;
          float v = acc[m][n][j] + bs;
          if (EPI == 1) v = 0.5f * v * (1.0f + erff(v * 0.70710678118f));
          out[(size_t)grow * N + gcol] = f2bf(v);
        }
      }
    }
  } else {
    float* out = (float*)outp;
#pragma unroll
    for (int m = 0; m < 4; ++m) {
#pragma unroll
      for (int n = 0; n < 4; ++n) {
        int tok = n0 + wc * 64 + n * 16 + l15;
        int bb = tok >> 10, p = tok & 1023;
#pragma unroll
        for (int j = 0; j < 4; ++j) {
          int c = m0 + wr * 64 + m * 16 + kg * 4 + j;
          size_t addr = (((size_t)(bb * 384 + c)) << 10) + p;
          out[addr] = res[addr] + gamma[c] * (acc[m][n][j] + bias[c]);
        }
      }
    }
  }
}

// ---------------------------------------------------------------------------
extern "C" void kernel_launch(void* const* d_in, const int* in_sizes, int n_in,
                              void* d_out, int out_size, void* d_ws,
                              size_t ws_size, hipStream_t stream) {
  const float* x      = (const float*)d_in[0];
  const float* conv_w = (const float*)d_in[1];
  const float* conv_b = (const float*)d_in[2];
  const float* nxca_w = (const float*)d_in[3];
  const float* nxca_b = (const float*)d_in[4];
  const float* temp   = (const float*)d_in[5];
  const float* qkv_w  = (const float*)d_in[6];
  const float* qkv_b  = (const float*)d_in[7];
  const float* proj_w = (const float*)d_in[8];
  const float* proj_b = (const float*)d_in[9];
  const float* norm_w = (const float*)d_in[10];
  const float* norm_b = (const float*)d_in[11];
  const float* fc1_w  = (const float*)d_in[12];
  const float* fc1_b  = (const float*)d_in[13];
  const float* fc2_w  = (const float*)d_in[14];
  const float* fc2_b  = (const float*)d_in[15];
  const float* g_xca  = (const float*)d_in[16];
  const float* g_mlp  = (const float*)d_in[17];
  (void)in_sizes; (void)n_in; (void)out_size; (void)ws_size;

  char* ws = (char*)d_ws;
  float* xc  = (float*)(ws);                    // 50,331,648 B (f32 NCHW, shortcut)
  u16* Y     = (u16*)(ws + 50331648);           // 25,165,824 B
  u16* QKV   = (u16*)(ws + 75497472);           // 75,497,472 B
  u16* Obuf  = (u16*)(ws + 150994944);          // 25,165,824 B
  u16* H1    = QKV;                             // reuse QKV+O span: 100,663,296 B
  u16* wq    = (u16*)(ws + 176160768);
  u16* wp    = (u16*)(ws + 177045504);
  u16* w1    = (u16*)(ws + 177340416);
  u16* w2    = (u16*)(ws + 178520064);          // end: 179,699,712 B

  cvt_k<<<1728, 256, 0, stream>>>(qkv_w, wq, 442368);
  cvt_k<<<576, 256, 0, stream>>>(proj_w, wp, 147456);
  cvt_k<<<2304, 256, 0, stream>>>(fc1_w, w1, 589824);
  cvt_k<<<2304, 256, 0, stream>>>(fc2_w, w2, 589824);

  conv_k<<<49152, 256, 0, stream>>>(x, conv_w, conv_b, xc);
  ln_t_k<<<dim3(32, 32), 256, 0, stream>>>(xc, nxca_w, nxca_b, Y);
  gemm_k<0><<<dim3(9, 256), 256, 0, stream>>>(Y, wq, 32768, 1152, 384, qkv_b,
                                              nullptr, nullptr, QKV);
  normqk_k<<<8192, 256, 0, stream>>>(QKV);
  attn_k<<<dim3(16, 4, 32), 256, 0, stream>>>(QKV, Obuf, temp);
  gemm_k<2><<<dim3(256, 3), 256, 0, stream>>>(wp, Obuf, 384, 32768, 384,
                                              proj_b, g_xca, xc, xc);
  ln_t_k<<<dim3(32, 32), 256, 0, stream>>>(xc, norm_w, norm_b, Y);
  gemm_k<1><<<dim3(12, 256), 256, 0, stream>>>(Y, w1, 32768, 1536, 384, fc1_b,
                                               nullptr, nullptr, H1);
  gemm_k<2><<<dim3(256, 3), 256, 0, stream>>>(w2, H1, 384, 32768, 1536, fc2_b,
                                              g_mlp, xc, (float*)d_out);
}